// Round 1
// baseline (1108.756 us; speedup 1.0000x reference)
//
#include <hip/hip_runtime.h>

// LSTMPINN fused kernel, round 1: split-bf16 (hi+lo) MFMA, fp32 pointwise.
// N=65536 samples, H=128, 6 timesteps, 2 LSTM layers + 3x256 dense + out(4).

typedef __attribute__((ext_vector_type(8))) short bf16x8;
typedef __attribute__((ext_vector_type(4))) float f32x4;

#define TM 64          // samples per block
#define APAD 8
#define AS (256 + APAD) // A-plane row stride in ushorts (264*2B = 528B, 16B aligned)

// ws layout (ushort units): [hi plane][lo plane] per matrix
#define OFF_HH0 0        // 512x128
#define OFF_L1  131072   // 512x256 = cat(Wih1,Whh1)
#define OFF_D0  393216   // 256x256 (cols permuted: k<128 -> mean part)
#define OFF_D1  524288
#define OFF_D2  655360
#define OFF_OUT 786432   // 16x256 (rows 4..15 zero)

__device__ __forceinline__ unsigned short f2bf(float x) {
  union { float f; unsigned u; } v; v.f = x;
  unsigned r = v.u + 0x7fffu + ((v.u >> 16) & 1u);   // RNE
  return (unsigned short)(r >> 16);
}
__device__ __forceinline__ float bf2f(unsigned short b) {
  union { unsigned u; float f; } v; v.u = ((unsigned)b) << 16; return v.f;
}
__device__ __forceinline__ float sigm(float v) { return 1.f / (1.f + __expf(-v)); }
__device__ __forceinline__ float tanh_(float v) { return 1.f - 2.f / (__expf(2.f * v) + 1.f); }

// ---------------- prep: split all weight matrices into bf16 hi/lo planes ---------------
__global__ void prep_k(const float* __restrict__ Whh0, const float* __restrict__ Wih1,
                       const float* __restrict__ Whh1, const float* __restrict__ Wd0,
                       const float* __restrict__ Wd1, const float* __restrict__ Wd2,
                       const float* __restrict__ Wout, unsigned short* __restrict__ ws) {
  int id = blockIdx.x * 256 + threadIdx.x;
  if (id >= 397312) return;
  float w; int base, i, plane;
  if (id < 65536) {                       // W_hh_l0 [512][128]
    i = id; base = OFF_HH0; plane = 65536; w = Whh0[i];
  } else if (id < 196608) {               // B_l1 [512][256] = cat(Wih1, Whh1)
    i = id - 65536; base = OFF_L1; plane = 131072;
    int g = i >> 8, k = i & 255;
    w = (k < 128) ? Wih1[(g << 7) + k] : Whh1[(g << 7) + k - 128];
  } else if (id < 262144) {               // Bd0 [256][256], permute: our k<128 = mean
    i = id - 196608; base = OFF_D0; plane = 65536;
    int n = i >> 8, k = i & 255;
    w = Wd0[(n << 8) + ((k < 128) ? k + 128 : k - 128)];
  } else if (id < 327680) {               // Bd1
    i = id - 262144; base = OFF_D1; plane = 65536; w = Wd1[i];
  } else if (id < 393216) {               // Bd2
    i = id - 327680; base = OFF_D2; plane = 65536; w = Wd2[i];
  } else {                                // Bout [16][256], rows >=4 zero
    i = id - 393216; base = OFF_OUT; plane = 4096;
    int n = i >> 8, k = i & 255;
    w = (n < 4) ? Wout[(n << 8) + k] : 0.f;
  }
  unsigned short hi = f2bf(w);
  unsigned short lo = f2bf(w - bf2f(hi));
  ws[base + i] = hi;
  ws[base + plane + i] = lo;
}

// ---------------- register-tiled split-bf16 GEMM fragment loop ---------------
// A from LDS planes (hi/lo), B from global (L2-resident hi/lo planes).
// A-frag: lane reads A[16*m + (lane&15)][k0 + quad*8 .. +7]  (MFMA A layout)
// B-frag: lane reads W[cols[n] + (lane&15)][k0 + quad*8 .. +7] (MFMA B layout, B=W^T)
template <int NT>
__device__ __forceinline__ void gemm_frag(const unsigned short* __restrict__ Bhi,
                                          const unsigned short* __restrict__ Blo,
                                          int ldB, const int* cols, int kiters,
                                          const unsigned short (&Ah)[TM][AS],
                                          const unsigned short (&Al)[TM][AS],
                                          int l16, int quad, f32x4 (&acc)[4][8]) {
  for (int ki = 0; ki < kiters; ++ki) {
    const int k = ki * 32 + quad * 8;
    bf16x8 afh[4], afl[4];
#pragma unroll
    for (int m = 0; m < 4; ++m) {
      afh[m] = *(const bf16x8*)&Ah[16 * m + l16][k];
      afl[m] = *(const bf16x8*)&Al[16 * m + l16][k];
    }
#pragma unroll
    for (int n = 0; n < NT; ++n) {
      const size_t row = (size_t)(cols[n] + l16) * ldB + k;
      bf16x8 bh = *(const bf16x8*)(Bhi + row);
      bf16x8 bl = *(const bf16x8*)(Blo + row);
#pragma unroll
      for (int m = 0; m < 4; ++m) {
        acc[m][n] = __builtin_amdgcn_mfma_f32_16x16x32_bf16(afh[m], bh, acc[m][n], 0, 0, 0);
        acc[m][n] = __builtin_amdgcn_mfma_f32_16x16x32_bf16(afl[m], bh, acc[m][n], 0, 0, 0);
        acc[m][n] = __builtin_amdgcn_mfma_f32_16x16x32_bf16(afh[m], bl, acc[m][n], 0, 0, 0);
      }
    }
  }
}

#define ZERO_ACC(A)                                        \
  {                                                        \
    _Pragma("unroll") for (int m_ = 0; m_ < 4; ++m_)       \
    _Pragma("unroll") for (int n_ = 0; n_ < 8; ++n_)       \
        A[m_][n_] = (f32x4){0.f, 0.f, 0.f, 0.f};           \
  }

// ---------------- main fused kernel: 1 block = 64 samples, full network ---------------
__global__ __launch_bounds__(256, 1) void fused_k(
    const float* __restrict__ x, const float* __restrict__ y,
    const float* __restrict__ Wih0, const float* __restrict__ b0,
    const float* __restrict__ b1, const float* __restrict__ bd0,
    const float* __restrict__ bd1, const float* __restrict__ bd2,
    const float* __restrict__ bout, const unsigned short* __restrict__ wsu,
    float* __restrict__ out) {
  __shared__ unsigned short Ahi[TM][AS];  // [s][0:128)=h0 (later mean), [128:256)=h1 (later last/a)
  __shared__ unsigned short Alo[TM][AS];
  __shared__ float feats[6][TM];
  __shared__ float sWih0[512], sb0[512], sb1[512];
  __shared__ float sbd[3][256];
  __shared__ float sbout[4];

  const int tid = threadIdx.x;
  const int wv = tid >> 6;     // wave 0..3
  const int lane = tid & 63;
  const int quad = lane >> 4;  // 0..3
  const int l16 = lane & 15;
  const int sb = blockIdx.x * TM;

  // stage bias tables + input features
  for (int i = tid; i < 512; i += 256) { sWih0[i] = Wih0[i]; sb0[i] = b0[i]; sb1[i] = b1[i]; }
  if (tid < 256) { sbd[0][tid] = bd0[tid]; sbd[1][tid] = bd1[tid]; sbd[2][tid] = bd2[tid]; }
  if (tid < 4) sbout[tid] = bout[tid];
  if (tid < TM) {
    float xn = 2.f * x[sb + tid] - 1.f;
    float yn = 2.f * y[sb + tid] - 1.f;
    feats[0][tid] = xn; feats[1][tid] = yn; feats[2][tid] = xn + yn;
    feats[3][tid] = xn - yn; feats[4][tid] = xn * yn; feats[5][tid] = xn * xn + yn * yn;
  }
  __syncthreads();

  // per-lane hoisted W_ih_l0 / bias values: gate type c, sub-tile s2 -> col = 128c+32wv+16s2+l16
  float wih0v[4][2], b0v[4][2], b1v[4][2];
#pragma unroll
  for (int c = 0; c < 4; ++c)
#pragma unroll
    for (int s2 = 0; s2 < 2; ++s2) {
      int j = 128 * c + 32 * wv + 16 * s2 + l16;
      wih0v[c][s2] = sWih0[j]; b0v[c][s2] = sb0[j]; b1v[c][s2] = sb1[j];
    }

  // per-lane state: [m][r][s2] -> sample s=16m+4quad+r, unit u=32wv+16s2+l16
  float c0[4][4][2], c1[4][4][2], meanh[4][4][2];
#pragma unroll
  for (int m = 0; m < 4; ++m)
#pragma unroll
    for (int r = 0; r < 4; ++r)
#pragma unroll
      for (int s2 = 0; s2 < 2; ++s2) { c0[m][r][s2] = 0.f; c1[m][r][s2] = 0.f; meanh[m][r][s2] = 0.f; }

  // LSTM n-tile columns: all 4 gate types, strided so pointwise stays in-lane
  int colsL[8];
#pragma unroll
  for (int c = 0; c < 4; ++c)
#pragma unroll
    for (int s2 = 0; s2 < 2; ++s2) colsL[2 * c + s2] = 128 * c + 32 * wv + 16 * s2;

  f32x4 acc[4][8];

  for (int t = 0; t < 6; ++t) {
    // ---- layer 0: gates = h0_{t-1} @ Whh0^T (+ x_t*Wih0 + b0 in pointwise) ----
    ZERO_ACC(acc);
    if (t > 0)
      gemm_frag<8>(wsu + OFF_HH0, wsu + OFF_HH0 + 65536, 128, colsL, 4, Ahi, Alo, l16, quad, acc);
    __syncthreads();  // all waves done reading h0_{t-1}
#pragma unroll
    for (int m = 0; m < 4; ++m)
#pragma unroll
      for (int r = 0; r < 4; ++r) {
        const int s = 16 * m + 4 * quad + r;
        const float xf = feats[t][s];
#pragma unroll
        for (int s2 = 0; s2 < 2; ++s2) {
          float ig = acc[m][0 + s2][r] + xf * wih0v[0][s2] + b0v[0][s2];
          float fg = acc[m][2 + s2][r] + xf * wih0v[1][s2] + b0v[1][s2];
          float gg = acc[m][4 + s2][r] + xf * wih0v[2][s2] + b0v[2][s2];
          float og = acc[m][6 + s2][r] + xf * wih0v[3][s2] + b0v[3][s2];
          float iv = sigm(ig), fv = sigm(fg), gv = tanh_(gg), ov = sigm(og);
          float cc = fv * c0[m][r][s2] + iv * gv;
          c0[m][r][s2] = cc;
          float h = ov * tanh_(cc);
          int u = 32 * wv + 16 * s2 + l16;
          unsigned short hh = f2bf(h);
          Ahi[s][u] = hh;
          Alo[s][u] = f2bf(h - bf2f(hh));
        }
      }
    __syncthreads();  // h0_t visible

    // ---- layer 1: gates = [h0_t ; h1_{t-1}] @ [Wih1;Whh1]^T + b1 ----
    ZERO_ACC(acc);
    gemm_frag<8>(wsu + OFF_L1, wsu + OFF_L1 + 131072, 256, colsL, (t == 0) ? 4 : 8,
                 Ahi, Alo, l16, quad, acc);
    __syncthreads();
#pragma unroll
    for (int m = 0; m < 4; ++m)
#pragma unroll
      for (int r = 0; r < 4; ++r) {
        const int s = 16 * m + 4 * quad + r;
#pragma unroll
        for (int s2 = 0; s2 < 2; ++s2) {
          float ig = acc[m][0 + s2][r] + b1v[0][s2];
          float fg = acc[m][2 + s2][r] + b1v[1][s2];
          float gg = acc[m][4 + s2][r] + b1v[2][s2];
          float og = acc[m][6 + s2][r] + b1v[3][s2];
          float iv = sigm(ig), fv = sigm(fg), gv = tanh_(gg), ov = sigm(og);
          float cc = fv * c1[m][r][s2] + iv * gv;
          c1[m][r][s2] = cc;
          float h = ov * tanh_(cc);
          int u = 32 * wv + 16 * s2 + l16;
          unsigned short hh = f2bf(h);
          Ahi[s][128 + u] = hh;            // h1 slot (becomes "last" for dense)
          Alo[s][128 + u] = f2bf(h - bf2f(hh));
          float mn = meanh[m][r][s2] + h;
          meanh[m][r][s2] = mn;
          if (t == 5) {                    // write mean into dead h0 slot
            mn *= (1.f / 6.f);
            unsigned short mh = f2bf(mn);
            Ahi[s][u] = mh;
            Alo[s][u] = f2bf(mn - bf2f(mh));
          }
        }
      }
    __syncthreads();
  }

  // ---- dense head: 3 layers of tanh(a @ Wd^T + bd), A-plane holds [mean|last] then a ----
  int colsD[4];
#pragma unroll
  for (int n = 0; n < 4; ++n) colsD[n] = 64 * wv + 16 * n;

  for (int layer = 0; layer < 3; ++layer) {
    const int base = (layer == 0) ? OFF_D0 : ((layer == 1) ? OFF_D1 : OFF_D2);
    ZERO_ACC(acc);
    gemm_frag<4>(wsu + base, wsu + base + 65536, 256, colsD, 8, Ahi, Alo, l16, quad, acc);
    __syncthreads();  // all waves done reading previous activations
#pragma unroll
    for (int m = 0; m < 4; ++m)
#pragma unroll
      for (int r = 0; r < 4; ++r) {
        const int s = 16 * m + 4 * quad + r;
#pragma unroll
        for (int n = 0; n < 4; ++n) {
          int col = colsD[n] + l16;
          float a = tanh_(acc[m][n][r] + sbd[layer][col]);
          unsigned short ah = f2bf(a);
          Ahi[s][col] = ah;
          Alo[s][col] = f2bf(a - bf2f(ah));
        }
      }
    __syncthreads();
  }

  // ---- output layer: wave wv handles m-tile wv (16 samples), 4 valid cols ----
  {
    f32x4 oacc = {0.f, 0.f, 0.f, 0.f};
    const unsigned short* Boh = wsu + OFF_OUT;
    const unsigned short* Bol = wsu + OFF_OUT + 4096;
    for (int ki = 0; ki < 8; ++ki) {
      int k = ki * 32 + quad * 8;
      bf16x8 ah = *(const bf16x8*)&Ahi[16 * wv + l16][k];
      bf16x8 al = *(const bf16x8*)&Alo[16 * wv + l16][k];
      bf16x8 bh = *(const bf16x8*)(Boh + (size_t)l16 * 256 + k);
      bf16x8 bl = *(const bf16x8*)(Bol + (size_t)l16 * 256 + k);
      oacc = __builtin_amdgcn_mfma_f32_16x16x32_bf16(ah, bh, oacc, 0, 0, 0);
      oacc = __builtin_amdgcn_mfma_f32_16x16x32_bf16(al, bh, oacc, 0, 0, 0);
      oacc = __builtin_amdgcn_mfma_f32_16x16x32_bf16(ah, bl, oacc, 0, 0, 0);
    }
#pragma unroll
    for (int r = 0; r < 4; ++r) {
      if (l16 < 4) {
        int s = sb + 16 * wv + 4 * quad + r;
        out[s * 4 + l16] = oacc[r] + sbout[l16];
      }
    }
  }
}

extern "C" void kernel_launch(void* const* d_in, const int* in_sizes, int n_in,
                              void* d_out, int out_size, void* d_ws, size_t ws_size,
                              hipStream_t stream) {
  (void)in_sizes; (void)n_in; (void)out_size; (void)ws_size;
  const float* x    = (const float*)d_in[0];
  const float* y    = (const float*)d_in[1];
  const float* Wih0 = (const float*)d_in[2];
  const float* Whh0 = (const float*)d_in[3];
  const float* b0   = (const float*)d_in[4];
  const float* Wih1 = (const float*)d_in[5];
  const float* Whh1 = (const float*)d_in[6];
  const float* b1   = (const float*)d_in[7];
  const float* Wd0  = (const float*)d_in[8];
  const float* bd0  = (const float*)d_in[9];
  const float* Wd1  = (const float*)d_in[10];
  const float* bd1  = (const float*)d_in[11];
  const float* Wd2  = (const float*)d_in[12];
  const float* bd2  = (const float*)d_in[13];
  const float* Wout = (const float*)d_in[14];
  const float* bout = (const float*)d_in[15];
  unsigned short* ws = (unsigned short*)d_ws;
  float* out = (float*)d_out;

  prep_k<<<dim3(1552), dim3(256), 0, stream>>>(Whh0, Wih1, Whh1, Wd0, Wd1, Wd2, Wout, ws);
  fused_k<<<dim3(65536 / TM), dim3(256), 0, stream>>>(x, y, Wih0, b0, b1, bd0, bd1, bd2,
                                                      bout, ws, out);
}